// Round 7
// baseline (1363.047 us; speedup 1.0000x reference)
//
#include <hip/hip_runtime.h>
#include <math.h>

#define DIN 32
#define DL 128
#define DOUT 10

typedef _Float16 f16x8 __attribute__((ext_vector_type(8)));
typedef float f32x4 __attribute__((ext_vector_type(4)));

__device__ __forceinline__ float sigm(float x){ return 1.0f/(1.0f+expf(-x)); }
__device__ __forceinline__ float softplus_(float x){ return fmaxf(x,0.0f) + log1pf(expf(-fabsf(x))); }

// ================= graph preprocessing =================
__global__ void count_edges_k(const int* __restrict__ ei, int* __restrict__ cnt, int E){
    int e = blockIdx.x*256 + threadIdx.x;
    if (e < E) atomicAdd(&cnt[ei[E + e]], 1);   // dst = ei[1][e]
}

__global__ void dinv_k(const int* __restrict__ cnt, float* __restrict__ dinv, int N){
    int i = blockIdx.x*256 + threadIdx.x;
    if (i < N) dinv[i] = rsqrtf((float)cnt[i] + 1.0f);
}

__global__ void block_sum_k(const int* __restrict__ cnt, int* __restrict__ bsum, int n){
    __shared__ int ws_[4];
    int tid = threadIdx.x;
    int i = blockIdx.x*256 + tid;
    int v = (i < n) ? cnt[i] : 0;
    #pragma unroll
    for (int off = 32; off > 0; off >>= 1) v += __shfl_xor(v, off);
    if ((tid & 63) == 0) ws_[tid >> 6] = v;
    __syncthreads();
    if (tid == 0) bsum[blockIdx.x] = ws_[0] + ws_[1] + ws_[2] + ws_[3];
}

__global__ void scan_bsum_k(int* __restrict__ bsum, int nb){
    __shared__ int tmp[1024];
    int tid = threadIdx.x;
    int v = (tid < nb) ? bsum[tid] : 0;
    tmp[tid] = v; __syncthreads();
    for (int off = 1; off < 1024; off <<= 1){
        int t = (tid >= off) ? tmp[tid-off] : 0;
        __syncthreads();
        tmp[tid] += t;
        __syncthreads();
    }
    if (tid < nb) bsum[tid] = tmp[tid] - v;   // exclusive
}

__global__ void block_scan_k(const int* __restrict__ cnt, const int* __restrict__ bexcl,
                             int* __restrict__ cursor, int* __restrict__ rowptr, int n){
    __shared__ int tmp[256];
    int tid = threadIdx.x;
    int i = blockIdx.x*256 + tid;
    int v = (i < n) ? cnt[i] : 0;
    tmp[tid] = v; __syncthreads();
    for (int off = 1; off < 256; off <<= 1){
        int t = (tid >= off) ? tmp[tid-off] : 0;
        __syncthreads();
        tmp[tid] += t;
        __syncthreads();
    }
    int excl = bexcl[blockIdx.x] + tmp[tid] - v;
    if (i < n){ cursor[i] = excl; rowptr[i+1] = excl + v; }
    if (i == 0) rowptr[0] = 0;
}

__global__ void place_edges_k(const int* __restrict__ ei, int* __restrict__ cursor,
                              int* __restrict__ csr_src, int E){
    int e = blockIdx.x*256 + threadIdx.x;
    if (e < E){
        int s = ei[e], d = ei[E + e];
        csr_src[atomicAdd(&cursor[d], 1)] = s;
    }
}

// ================= weight prep: fp32 [K][C] -> fp16 transposed [C][K] =================
struct WPA { const float* s; _Float16* d; int K; int C; };
struct WPA14 { WPA a[14]; };
__global__ void wprep_all_k(WPA14 args){
    WPA w = args.a[blockIdx.y];
    int idx = blockIdx.x*256 + threadIdx.x;
    if (idx < w.K*w.C){ int k = idx / w.C, c = idx % w.C; w.d[(size_t)c*w.K + k] = (_Float16)w.s[idx]; }
}

// ================= round-3 style MFMA helpers (for input layer + decoder) =============
template<int K, int NC16, bool ZERO>
__device__ __forceinline__ void mfma_ldsmm(const _Float16* As, int lda,
        const _Float16* Ws, int ldw, f32x4 (&acc)[2][8], int ln, int q, int wid){
    if (ZERO){
        #pragma unroll
        for (int r = 0; r < 2; ++r)
            #pragma unroll
            for (int c = 0; c < 8; ++c) acc[r][c] = (f32x4){0.f,0.f,0.f,0.f};
    }
    #pragma unroll
    for (int kk = 0; kk < K/32; ++kk){
        int ko = kk*32 + q*8;
        f16x8 a0 = *(const f16x8*)&As[(size_t)(wid*32 + ln)*lda + ko];
        f16x8 a1 = *(const f16x8*)&As[(size_t)(wid*32 + 16 + ln)*lda + ko];
        #pragma unroll
        for (int c = 0; c < NC16; ++c){
            f16x8 b = *(const f16x8*)&Ws[(size_t)(c*16 + ln)*ldw + ko];
            acc[0][c] = __builtin_amdgcn_mfma_f32_16x16x32_f16(a0, b, acc[0][c], 0, 0, 0);
            acc[1][c] = __builtin_amdgcn_mfma_f32_16x16x32_f16(a1, b, acc[1][c], 0, 0, 0);
        }
    }
}

// ACT: 0 none, 1 sigmoid, 2 relu
template<int NC16, int ACT>
__device__ __forceinline__ void act_store_lds(_Float16* D, int ldd, f32x4 (&acc)[2][8],
        const float* bias, int ln, int q, int wid){
    #pragma unroll
    for (int r = 0; r < 2; ++r){
        int rowb = wid*32 + r*16 + q*4;
        #pragma unroll
        for (int c = 0; c < NC16; ++c){
            int col = c*16 + ln;
            float bv = bias ? bias[col] : 0.0f;
            #pragma unroll
            for (int i2 = 0; i2 < 4; ++i2){
                float v = acc[r][c][i2] + bv;
                if (ACT == 1) v = sigm(v);
                else if (ACT == 2) v = fmaxf(v, 0.0f);
                D[(size_t)(rowb + i2)*ldd + col] = (_Float16)v;
            }
        }
    }
}

__device__ __forceinline__ void stage_w(const _Float16* Wg, _Float16* Wl, int ldw,
                                        int C, int K, int tid){
    int kq = K/8, tot = C*kq;
    for (int i = tid; i < tot; i += 256){
        int r = i/kq, s = i%kq;
        *(f16x8*)&Wl[(size_t)r*ldw + s*8] = *(const f16x8*)&Wg[(size_t)r*K + s*8];
    }
}

// ================= fused input layer: g = (sigmoid(x@Win+bin)) @ Wgcn =================
__global__ __launch_bounds__(256,1) void fused_input_k(const float* __restrict__ x,
        const _Float16* __restrict__ WtIN, const float* __restrict__ b_in,
        const _Float16* __restrict__ WtGCN, _Float16* __restrict__ gOut, int nrows){
    __shared__ __align__(16) _Float16 Ax[128*40];
    __shared__ __align__(16) _Float16 Hl[128*136];
    __shared__ __align__(16) _Float16 Wi[128*40];
    __shared__ __align__(16) _Float16 Wg[128*136];
    int tid = threadIdx.x, lane = tid & 63, wid = tid >> 6;
    int ln = lane & 15, q = lane >> 4;
    int row0 = blockIdx.x * 128;
    for (int i = tid; i < 512; i += 256){
        int r = i >> 2, s = i & 3;
        f16x8 v = {};
        if (row0 + r < nrows){
            const float* xs = &x[(size_t)(row0+r)*DIN + s*8];
            float4 u0 = *(const float4*)xs, u1 = *(const float4*)(xs+4);
            v[0]=(_Float16)u0.x; v[1]=(_Float16)u0.y; v[2]=(_Float16)u0.z; v[3]=(_Float16)u0.w;
            v[4]=(_Float16)u1.x; v[5]=(_Float16)u1.y; v[6]=(_Float16)u1.z; v[7]=(_Float16)u1.w;
        }
        *(f16x8*)&Ax[r*40 + s*8] = v;
        *(f16x8*)&Wi[r*40 + s*8] = *(const f16x8*)&WtIN[(size_t)r*32 + s*8];
    }
    for (int i = tid; i < 2048; i += 256){
        int r = i >> 4, s = i & 15;
        *(f16x8*)&Wg[r*136 + s*8] = *(const f16x8*)&WtGCN[(size_t)r*128 + s*8];
    }
    __syncthreads();
    f32x4 acc[2][8];
    mfma_ldsmm<32,8,true>(Ax, 40, Wi, 40, acc, ln, q, wid);
    act_store_lds<8,1>(Hl, 136, acc, b_in, ln, q, wid);
    __syncthreads();
    mfma_ldsmm<128,8,true>(Hl, 136, Wg, 136, acc, ln, q, wid);
    #pragma unroll
    for (int r = 0; r < 2; ++r){
        int rowb = row0 + wid*32 + r*16 + q*4;
        #pragma unroll
        for (int c = 0; c < 8; ++c){
            int col = c*16 + ln;
            #pragma unroll
            for (int i2 = 0; i2 < 4; ++i2){
                int row = rowb + i2;
                if (row < nrows) gOut[(size_t)row*DL + col] = (_Float16)acc[r][c][i2];
            }
        }
    }
}

// ================= GCN aggregation (fp16 feats, fp32 accum, unroll-4) =================
__global__ __launch_bounds__(256) void gcn_agg_h(const _Float16* __restrict__ g,
        _Float16* __restrict__ out, const int* __restrict__ rowptr,
        const int* __restrict__ csr_src, const float* __restrict__ dinv,
        const float* __restrict__ bgcn, int N){
    int t = threadIdx.x;
    int node = blockIdx.x*16 + (t >> 4);
    int f = (t & 15)*8;
    if (node >= N) return;
    float dv = dinv[node];
    float sn = dv*dv;
    f16x8 sv = *(const f16x8*)&g[(size_t)node*DL + f];
    float acc[8];
    #pragma unroll
    for (int j = 0; j < 8; ++j) acc[j] = (float)sv[j]*sn + bgcn[f+j];
    int e = rowptr[node], e1 = rowptr[node+1];
    for (; e + 4 <= e1; e += 4){
        int s0 = csr_src[e], s1 = csr_src[e+1], s2 = csr_src[e+2], s3 = csr_src[e+3];
        float w0 = dinv[s0]*dv, w1 = dinv[s1]*dv, w2 = dinv[s2]*dv, w3 = dinv[s3]*dv;
        f16x8 n0 = *(const f16x8*)&g[(size_t)s0*DL + f];
        f16x8 n1 = *(const f16x8*)&g[(size_t)s1*DL + f];
        f16x8 n2 = *(const f16x8*)&g[(size_t)s2*DL + f];
        f16x8 n3 = *(const f16x8*)&g[(size_t)s3*DL + f];
        #pragma unroll
        for (int j = 0; j < 8; ++j)
            acc[j] += (float)n0[j]*w0 + (float)n1[j]*w1 + (float)n2[j]*w2 + (float)n3[j]*w3;
    }
    for (; e < e1; ++e){
        int s = csr_src[e];
        float w = dinv[s]*dv;
        f16x8 nv = *(const f16x8*)&g[(size_t)s*DL + f];
        #pragma unroll
        for (int j = 0; j < 8; ++j) acc[j] += (float)nv[j]*w;
    }
    f16x8 o;
    #pragma unroll
    for (int j = 0; j < 8; ++j) o[j] = (_Float16)acc[j];
    *(f16x8*)&out[(size_t)node*DL + f] = o;
}

// ================= fused hop: register-resident activation chain =====================
// Each wave owns 16 rows; act lives in per-wave LDS scratch; only W is coop-staged.
// Wt8: m=0 gcn, 1..5 enc0..4, 6 mu, 7 std (each [128 cols][128 k] fp16)
// LDS = 34 KB (W) + 34 KB (scratch) = 68 KB -> 2 blocks/CU @ 512 thr = 16 waves/CU.
// VGPR budget: layers are computed as two 64-col half-GEMMs (acc4 = 16 VGPRs), halves
// buffered as f16 until both gemms finished READING the in-place LDS rows. Round-6
// PMC showed full-width acc[8] hit the 128-VGPR cap and spilled (139 MB scratch wr).
template<int LAST>
__global__ __launch_bounds__(512,2) void hop_reg_k(const _Float16* __restrict__ g2,
        const _Float16* __restrict__ Wt8, const float* __restrict__ b_enc,
        const float* __restrict__ b_mu, const float* __restrict__ b_std,
        const float* __restrict__ eps_i, _Float16* __restrict__ gOut,
        float* __restrict__ muOut, float* __restrict__ stdOut,
        _Float16* __restrict__ hOut, int nrows){
    __shared__ __align__(16) _Float16 Wb[128*136];
    __shared__ __align__(16) _Float16 Sc[8*16*136];
    int tid = threadIdx.x, lane = tid & 63, wid = tid >> 6;
    int ln = lane & 15, q = lane >> 4;
    int row0 = blockIdx.x*128;
    _Float16* mySc = Sc + wid*16*136;
    int wrow0 = row0 + wid*16;

    // stage this wave's 16 act rows (own rows only -> no barrier needed)
    #pragma unroll
    for (int i = 0; i < 4; ++i){
        int gg = lane + i*64;                 // 0..255 granules of 16B
        int r = gg >> 4, s = gg & 15;
        f16x8 v = {};
        if (wrow0 + r < nrows) v = *(const f16x8*)&g2[(size_t)(wrow0+r)*DL + s*8];
        *(f16x8*)&mySc[r*136 + s*8] = v;
    }

    auto stageW = [&](int m){
        __syncthreads();                      // all waves done reading previous W
        const _Float16* Wg = Wt8 + (size_t)m*16384;
        #pragma unroll
        for (int i = 0; i < 4; ++i){
            int gg = tid + i*512;             // 2048 granules of 16B
            int r = gg >> 4, s = gg & 15;
            *(f16x8*)&Wb[r*136 + s*8] = *(const f16x8*)&Wg[(size_t)r*128 + s*8];
        }
        __syncthreads();
    };
    // 64-col half GEMM: acc4 = 16 VGPRs
    auto gemmHalf = [&](int half, f32x4 (&a4)[4]){
        #pragma unroll
        for (int c = 0; c < 4; ++c) a4[c] = (f32x4){0.f,0.f,0.f,0.f};
        #pragma unroll
        for (int kk = 0; kk < 4; ++kk){
            f16x8 a = *(const f16x8*)&mySc[ln*136 + kk*32 + q*8];
            #pragma unroll
            for (int c = 0; c < 4; ++c){
                f16x8 b = *(const f16x8*)&Wb[((half*4 + c)*16 + ln)*136 + kk*32 + q*8];
                a4[c] = __builtin_amdgcn_mfma_f32_16x16x32_f16(a, b, a4[c], 0, 0, 0);
            }
        }
    };

    _Float16 hbuf[2][16];   // [half][c*4+i2] buffered layer output (16 VGPRs)
    _Float16 svr[2][16];    // std values (16 VGPRs)
    f32x4 acc4[4];

    // 5 encoder layers (sigmoid), in-place on the wave's scratch rows
    #pragma unroll 1
    for (int j = 0; j < 5; ++j){
        stageW(1+j);
        #pragma unroll
        for (int half = 0; half < 2; ++half){
            gemmHalf(half, acc4);
            #pragma unroll
            for (int c = 0; c < 4; ++c){
                float bv = b_enc[j*DL + half*64 + c*16 + ln];
                #pragma unroll
                for (int i2 = 0; i2 < 4; ++i2)
                    hbuf[half][c*4+i2] = (_Float16)sigm(acc4[c][i2] + bv);
            }
        }
        // both halves have finished reading mySc -> safe in-place write
        #pragma unroll
        for (int half = 0; half < 2; ++half)
            #pragma unroll
            for (int c = 0; c < 4; ++c)
                #pragma unroll
                for (int i2 = 0; i2 < 4; ++i2)
                    mySc[(q*4+i2)*136 + half*64 + c*16 + ln] = hbuf[half][c*4+i2];
    }
    // std = softplus(src@Wstd + b - 5) -> svr regs (no mySc write)
    stageW(7);
    #pragma unroll
    for (int half = 0; half < 2; ++half){
        gemmHalf(half, acc4);
        #pragma unroll
        for (int c = 0; c < 4; ++c){
            int col = half*64 + c*16 + ln;
            float bs = b_std[col];
            #pragma unroll
            for (int i2 = 0; i2 < 4; ++i2){
                float s = softplus_(acc4[c][i2] + bs - 5.0f);
                svr[half][c*4+i2] = (_Float16)s;
                if (LAST){
                    int grow = wrow0 + q*4 + i2;
                    if (grow < nrows) stdOut[(size_t)grow*DL + col] = s;
                }
            }
        }
    }
    // mu, then h = mu + std*eps -> mySc
    stageW(6);
    #pragma unroll
    for (int half = 0; half < 2; ++half){
        gemmHalf(half, acc4);
        #pragma unroll
        for (int c = 0; c < 4; ++c){
            int col = half*64 + c*16 + ln;
            float bm = b_mu[col];
            #pragma unroll
            for (int i2 = 0; i2 < 4; ++i2){
                int grow = wrow0 + q*4 + i2;
                float mv = acc4[c][i2] + bm;
                float ev = (grow < nrows) ? eps_i[(size_t)grow*DL + col] : 0.0f;
                hbuf[half][c*4+i2] = (_Float16)(mv + (float)svr[half][c*4+i2]*ev);
                if (LAST && grow < nrows) muOut[(size_t)grow*DL + col] = mv;
            }
        }
    }
    #pragma unroll
    for (int half = 0; half < 2; ++half)
        #pragma unroll
        for (int c = 0; c < 4; ++c)
            #pragma unroll
            for (int i2 = 0; i2 < 4; ++i2)
                mySc[(q*4+i2)*136 + half*64 + c*16 + ln] = hbuf[half][c*4+i2];

    if (LAST){
        // coalesced h -> global
        #pragma unroll
        for (int i = 0; i < 4; ++i){
            int gg = lane + i*64;
            int r = gg >> 4, s = gg & 15;
            if (wrow0 + r < nrows)
                *(f16x8*)&hOut[(size_t)(wrow0+r)*DL + s*8] = *(const f16x8*)&mySc[r*136 + s*8];
        }
    } else {
        // g = h @ Wgcn, then coalesced g -> global
        stageW(0);
        #pragma unroll
        for (int half = 0; half < 2; ++half){
            gemmHalf(half, acc4);
            #pragma unroll
            for (int c = 0; c < 4; ++c)
                #pragma unroll
                for (int i2 = 0; i2 < 4; ++i2)
                    hbuf[half][c*4+i2] = (_Float16)acc4[c][i2];
        }
        #pragma unroll
        for (int half = 0; half < 2; ++half)
            #pragma unroll
            for (int c = 0; c < 4; ++c)
                #pragma unroll
                for (int i2 = 0; i2 < 4; ++i2)
                    mySc[(q*4+i2)*136 + half*64 + c*16 + ln] = hbuf[half][c*4+i2];
        #pragma unroll
        for (int i = 0; i < 4; ++i){
            int gg = lane + i*64;
            int r = gg >> 4, s = gg & 15;
            if (wrow0 + r < nrows)
                *(f16x8*)&gOut[(size_t)(wrow0+r)*DL + s*8] = *(const f16x8*)&mySc[r*136 + s*8];
        }
    }
}

// ================= fused decoder (round-3 style, LDS-staged weights) ==================
__global__ __launch_bounds__(256,1) void decoder_k(const _Float16* __restrict__ h,
        const _Float16* __restrict__ WtD0, const _Float16* __restrict__ WtD1,
        const _Float16* __restrict__ WtD2, const _Float16* __restrict__ WtD3,
        const _Float16* __restrict__ WtD4,
        const float* __restrict__ bd0, const float* __restrict__ bd1,
        const float* __restrict__ bd2, const float* __restrict__ bd3,
        const float* __restrict__ bd4, const float* __restrict__ Wo,
        const float* __restrict__ bo, const int* __restrict__ batch,
        float* __restrict__ sums, float* __restrict__ gcnt, int nrows){
    __shared__ __align__(16) _Float16 A[128*136];
    __shared__ __align__(16) _Float16 B[128*264];
    __shared__ __align__(16) _Float16 W[128*136];
    __shared__ float WoL[16*DOUT];
    __shared__ float boL[DOUT];
    int tid = threadIdx.x, lane = tid & 63, wid = tid >> 6;
    int ln = lane & 15, q = lane >> 4;
    int row0 = blockIdx.x * 128;
    for (int i = tid; i < 2048; i += 256){
        int r = i >> 4, s = i & 15;
        f16x8 v = {};
        if (row0 + r < nrows) v = *(const f16x8*)&h[(size_t)(row0+r)*DL + s*8];
        *(f16x8*)&A[r*136 + s*8] = v;
    }
    if (tid < 16*DOUT) WoL[tid] = Wo[tid];
    if (tid < DOUT) boL[tid] = bo[tid];
    f32x4 acc[2][8];
    // d0: 128 -> 256 (two col-halves)
    for (int ch = 0; ch < 2; ++ch){
        stage_w(WtD0 + (size_t)ch*128*128, W, 136, 128, 128, tid);
        __syncthreads();
        mfma_ldsmm<128,8,true>(A, 136, W, 136, acc, ln, q, wid);
        act_store_lds<8,2>(B + ch*128, 264, acc, bd0 + ch*128, ln, q, wid);
        __syncthreads();
    }
    // d1: 256 -> 128 (two K-halves, accumulate)
    for (int kh = 0; kh < 2; ++kh){
        for (int i = tid; i < 2048; i += 256){
            int r = i >> 4, s = i & 15;
            *(f16x8*)&W[r*136 + s*8] = *(const f16x8*)&WtD1[(size_t)r*256 + kh*128 + s*8];
        }
        __syncthreads();
        if (kh == 0) mfma_ldsmm<128,8,true >(B,       264, W, 136, acc, ln, q, wid);
        else         mfma_ldsmm<128,8,false>(B + 128, 264, W, 136, acc, ln, q, wid);
        __syncthreads();
    }
    act_store_lds<8,2>(A, 136, acc, bd1, ln, q, wid);
    __syncthreads();
    // d2: 128 -> 64
    stage_w(WtD2, W, 136, 64, 128, tid);
    __syncthreads();
    mfma_ldsmm<128,4,true>(A, 136, W, 136, acc, ln, q, wid);
    act_store_lds<4,2>(B, 264, acc, bd2, ln, q, wid);
    __syncthreads();
    // d3: 64 -> 32
    stage_w(WtD3, W, 136, 32, 64, tid);
    __syncthreads();
    mfma_ldsmm<64,2,true>(B, 264, W, 136, acc, ln, q, wid);
    act_store_lds<2,2>(A, 136, acc, bd3, ln, q, wid);
    __syncthreads();
    // d4: 32 -> 16
    stage_w(WtD4, W, 136, 16, 32, tid);
    __syncthreads();
    mfma_ldsmm<32,1,true>(A, 136, W, 136, acc, ln, q, wid);
    act_store_lds<1,2>(B, 264, acc, bd4, ln, q, wid);
    __syncthreads();
    // final 16 -> 10 sigmoid + mean-pool
    int node = row0 + tid;
    bool valid = (tid < 128) && (node < nrows);
    float yp[DOUT];
    int b = -1;
    if (valid){
        float dd[16];
        #pragma unroll
        for (int k = 0; k < 16; ++k) dd[k] = (float)B[(size_t)tid*264 + k];
        #pragma unroll
        for (int o = 0; o < DOUT; ++o){
            float a2 = boL[o];
            #pragma unroll
            for (int k = 0; k < 16; ++k) a2 += dd[k]*WoL[k*DOUT + o];
            yp[o] = sigm(a2);
        }
        b = batch[node];
    }
    int b0 = __builtin_amdgcn_readfirstlane(b);
    unsigned long long m = __ballot(b == b0);
    if (m == ~0ull && b0 >= 0){
        #pragma unroll
        for (int o = 0; o < DOUT; ++o){
            float v = yp[o];
            for (int off = 32; off > 0; off >>= 1) v += __shfl_xor(v, off);
            if ((tid & 63) == 0) atomicAdd(&sums[b0*DOUT + o], v);
        }
        if ((tid & 63) == 0) atomicAdd(&gcnt[b0], 64.0f);
    } else if (valid){
        #pragma unroll
        for (int o = 0; o < DOUT; ++o) atomicAdd(&sums[b*DOUT + o], yp[o]);
        atomicAdd(&gcnt[b], 1.0f);
    }
}

__global__ void divide_k(float* __restrict__ out, const float* __restrict__ gcnt, int n){
    int i = blockIdx.x*256 + threadIdx.x;
    if (i < n) out[i] = out[i] / fmaxf(gcnt[i/DOUT], 1.0f);
}

__global__ void copy_k(const float* __restrict__ src, float* __restrict__ dst, int n){
    int i = blockIdx.x*256 + threadIdx.x;
    if (i < n) dst[i] = src[i];
}

extern "C" void kernel_launch(void* const* d_in, const int* in_sizes, int n_in,
                              void* d_out, int out_size, void* d_ws, size_t ws_size,
                              hipStream_t stream) {
    const float* x     = (const float*)d_in[0];
    const int*   ei    = (const int*)d_in[1];
    const int*   batch = (const int*)d_in[2];
    const float* y     = (const float*)d_in[3];
    const float* eps   = (const float*)d_in[4];
    const float* W_in  = (const float*)d_in[5];
    const float* b_in  = (const float*)d_in[6];
    const float* W_gcn = (const float*)d_in[7];
    const float* b_gcn = (const float*)d_in[8];
    const float* W_enc = (const float*)d_in[9];
    const float* b_enc = (const float*)d_in[10];
    const float* W_mu  = (const float*)d_in[11];
    const float* b_mu  = (const float*)d_in[12];
    const float* W_std = (const float*)d_in[13];
    const float* b_std = (const float*)d_in[14];
    const float* Wd0 = (const float*)d_in[15]; const float* bd0 = (const float*)d_in[16];
    const float* Wd1 = (const float*)d_in[17]; const float* bd1 = (const float*)d_in[18];
    const float* Wd2 = (const float*)d_in[19]; const float* bd2 = (const float*)d_in[20];
    const float* Wd3 = (const float*)d_in[21]; const float* bd3 = (const float*)d_in[22];
    const float* Wd4 = (const float*)d_in[23]; const float* bd4 = (const float*)d_in[24];
    const float* Wo  = (const float*)d_in[25]; const float* bo  = (const float*)d_in[26];

    const int N = in_sizes[2];
    const int E = in_sizes[1]/2;
    const int G = in_sizes[3]/DOUT;
    const int KHOP = in_sizes[4] / (N*DL);   // = 3
    const size_t NN = (size_t)N*DL;

    char* p = (char*)d_ws;
    auto take = [&p](size_t bytes) -> char* {
        char* r = p; p += (bytes + 255) & ~(size_t)255; return r;
    };
    _Float16* hG  = (_Float16*)take(NN*2);
    _Float16* hG2 = (_Float16*)take(NN*2);
    _Float16* hH  = (_Float16*)take(NN*2);
    float* dinv  = (float*)take((size_t)N*4);
    float* gcnt  = (float*)take((size_t)G*4);
    int* cnt     = (int*)take((size_t)N*4);
    int* rowptr  = (int*)take((size_t)(N+1)*4);
    int* cursor  = (int*)take((size_t)N*4);
    int* csr_src = (int*)take((size_t)E*4);
    int* bsum    = (int*)take(1024*4);
    _Float16* Wt8  = (_Float16*)take((size_t)8*DL*DL*2);  // gcn, enc0..4, mu, std
    _Float16* WtIN = (_Float16*)take((size_t)DL*DIN*2);
    _Float16* WtD0 = (_Float16*)take((size_t)256*128*2);
    _Float16* WtD1 = (_Float16*)take((size_t)128*256*2);
    _Float16* WtD2 = (_Float16*)take((size_t)64*128*2);
    _Float16* WtD3 = (_Float16*)take((size_t)32*64*2);
    _Float16* WtD4 = (_Float16*)take((size_t)16*32*2);

    float* out_ypred = (float*)d_out;                    // [G,10]
    float* out_mu    = out_ypred + (size_t)G*DOUT;       // [N,128]
    float* out_std   = out_mu + NN;                      // [N,128]
    float* out_y     = out_std + NN;                     // [G,10]

    hipMemsetAsync(cnt, 0, sizeof(int)*N, stream);
    hipMemsetAsync(out_ypred, 0, sizeof(float)*G*DOUT, stream);
    hipMemsetAsync(gcnt, 0, sizeof(float)*G, stream);

    int gE = (E + 255)/256, gN = (N + 255)/256;
    int nb = gN;

    count_edges_k<<<gE, 256, 0, stream>>>(ei, cnt, E);
    dinv_k<<<gN, 256, 0, stream>>>(cnt, dinv, N);
    block_sum_k<<<nb, 256, 0, stream>>>(cnt, bsum, N);
    scan_bsum_k<<<1, 1024, 0, stream>>>(bsum, nb);
    block_scan_k<<<nb, 256, 0, stream>>>(cnt, bsum, cursor, rowptr, N);
    place_edges_k<<<gE, 256, 0, stream>>>(ei, cursor, csr_src, E);

    WPA14 wa;
    wa.a[0]  = { W_in,  WtIN, DIN, DL };
    wa.a[1]  = { W_gcn, Wt8,  DL, DL };
    for (int j = 0; j < 5; ++j) wa.a[2+j] = { W_enc + (size_t)j*DL*DL, Wt8 + (size_t)(1+j)*DL*DL, DL, DL };
    wa.a[7]  = { W_mu,  Wt8 + (size_t)6*DL*DL, DL, DL };
    wa.a[8]  = { W_std, Wt8 + (size_t)7*DL*DL, DL, DL };
    wa.a[9]  = { Wd0, WtD0, 128, 256 };
    wa.a[10] = { Wd1, WtD1, 256, 128 };
    wa.a[11] = { Wd2, WtD2, 128, 64 };
    wa.a[12] = { Wd3, WtD3, 64, 32 };
    wa.a[13] = { Wd4, WtD4, 32, 16 };
    wprep_all_k<<<dim3(128, 14), 256, 0, stream>>>(wa);

    int ntile = (N + 127)/128;
    fused_input_k<<<ntile, 256, 0, stream>>>(x, WtIN, b_in, Wt8, hG, N);

    for (int i = 0; i < KHOP; ++i){
        gcn_agg_h<<<(N+15)/16, 256, 0, stream>>>(hG, hG2, rowptr, csr_src, dinv, b_gcn, N);
        const float* eps_i = eps + (size_t)i*NN;
        if (i == KHOP-1)
            hop_reg_k<1><<<ntile, 512, 0, stream>>>(hG2, Wt8, b_enc, b_mu, b_std, eps_i,
                                                    nullptr, out_mu, out_std, hH, N);
        else
            hop_reg_k<0><<<ntile, 512, 0, stream>>>(hG2, Wt8, b_enc, b_mu, b_std, eps_i,
                                                    hG, nullptr, nullptr, nullptr, N);
    }

    decoder_k<<<ntile, 256, 0, stream>>>(hH, WtD0, WtD1, WtD2, WtD3, WtD4,
                                         bd0, bd1, bd2, bd3, bd4, Wo, bo,
                                         batch, out_ypred, gcnt, N);
    divide_k<<<(G*DOUT+255)/256, 256, 0, stream>>>(out_ypred, gcnt, G*DOUT);
    copy_k<<<(G*DOUT+255)/256, 256, 0, stream>>>(y, out_y, G*DOUT);
}

// Round 8
// 793.545 us; speedup vs baseline: 1.7177x; 1.7177x over previous
//
#include <hip/hip_runtime.h>
#include <math.h>

#define DIN 32
#define DL 128
#define DOUT 10

typedef _Float16 f16x8 __attribute__((ext_vector_type(8)));
typedef float f32x4 __attribute__((ext_vector_type(4)));

__device__ __forceinline__ float sigm(float x){ return 1.0f/(1.0f+expf(-x)); }
__device__ __forceinline__ float softplus_(float x){ return fmaxf(x,0.0f) + log1pf(expf(-fabsf(x))); }

// ================= graph preprocessing =================
__global__ void count_edges_k(const int* __restrict__ ei, int* __restrict__ cnt, int E){
    int e = blockIdx.x*256 + threadIdx.x;
    if (e < E) atomicAdd(&cnt[ei[E + e]], 1);   // dst = ei[1][e]
}

__global__ void dinv_k(const int* __restrict__ cnt, float* __restrict__ dinv, int N){
    int i = blockIdx.x*256 + threadIdx.x;
    if (i < N) dinv[i] = rsqrtf((float)cnt[i] + 1.0f);
}

__global__ void block_sum_k(const int* __restrict__ cnt, int* __restrict__ bsum, int n){
    __shared__ int ws_[4];
    int tid = threadIdx.x;
    int i = blockIdx.x*256 + tid;
    int v = (i < n) ? cnt[i] : 0;
    #pragma unroll
    for (int off = 32; off > 0; off >>= 1) v += __shfl_xor(v, off);
    if ((tid & 63) == 0) ws_[tid >> 6] = v;
    __syncthreads();
    if (tid == 0) bsum[blockIdx.x] = ws_[0] + ws_[1] + ws_[2] + ws_[3];
}

__global__ void scan_bsum_k(int* __restrict__ bsum, int nb){
    __shared__ int tmp[1024];
    int tid = threadIdx.x;
    int v = (tid < nb) ? bsum[tid] : 0;
    tmp[tid] = v; __syncthreads();
    for (int off = 1; off < 1024; off <<= 1){
        int t = (tid >= off) ? tmp[tid-off] : 0;
        __syncthreads();
        tmp[tid] += t;
        __syncthreads();
    }
    if (tid < nb) bsum[tid] = tmp[tid] - v;   // exclusive
}

__global__ void block_scan_k(const int* __restrict__ cnt, const int* __restrict__ bexcl,
                             int* __restrict__ cursor, int* __restrict__ rowptr, int n){
    __shared__ int tmp[256];
    int tid = threadIdx.x;
    int i = blockIdx.x*256 + tid;
    int v = (i < n) ? cnt[i] : 0;
    tmp[tid] = v; __syncthreads();
    for (int off = 1; off < 256; off <<= 1){
        int t = (tid >= off) ? tmp[tid-off] : 0;
        __syncthreads();
        tmp[tid] += t;
        __syncthreads();
    }
    int excl = bexcl[blockIdx.x] + tmp[tid] - v;
    if (i < n){ cursor[i] = excl; rowptr[i+1] = excl + v; }
    if (i == 0) rowptr[0] = 0;
}

__global__ void place_edges_k(const int* __restrict__ ei, int* __restrict__ cursor,
                              int* __restrict__ csr_src, int E){
    int e = blockIdx.x*256 + threadIdx.x;
    if (e < E){
        int s = ei[e], d = ei[E + e];
        csr_src[atomicAdd(&cursor[d], 1)] = s;
    }
}

// ================= weight prep: fp32 [K][C] -> fp16 transposed [C][K] =================
struct WPA { const float* s; _Float16* d; int K; int C; };
struct WPA14 { WPA a[14]; };
__global__ void wprep_all_k(WPA14 args){
    WPA w = args.a[blockIdx.y];
    int idx = blockIdx.x*256 + threadIdx.x;
    if (idx < w.K*w.C){ int k = idx / w.C, c = idx % w.C; w.d[(size_t)c*w.K + k] = (_Float16)w.s[idx]; }
}

// ================= round-3 style MFMA helpers =============
template<int K, int NC16, bool ZERO>
__device__ __forceinline__ void mfma_ldsmm(const _Float16* As, int lda,
        const _Float16* Ws, int ldw, f32x4 (&acc)[2][8], int ln, int q, int wid){
    if (ZERO){
        #pragma unroll
        for (int r = 0; r < 2; ++r)
            #pragma unroll
            for (int c = 0; c < 8; ++c) acc[r][c] = (f32x4){0.f,0.f,0.f,0.f};
    }
    #pragma unroll
    for (int kk = 0; kk < K/32; ++kk){
        int ko = kk*32 + q*8;
        f16x8 a0 = *(const f16x8*)&As[(size_t)(wid*32 + ln)*lda + ko];
        f16x8 a1 = *(const f16x8*)&As[(size_t)(wid*32 + 16 + ln)*lda + ko];
        #pragma unroll
        for (int c = 0; c < NC16; ++c){
            f16x8 b = *(const f16x8*)&Ws[(size_t)(c*16 + ln)*ldw + ko];
            acc[0][c] = __builtin_amdgcn_mfma_f32_16x16x32_f16(a0, b, acc[0][c], 0, 0, 0);
            acc[1][c] = __builtin_amdgcn_mfma_f32_16x16x32_f16(a1, b, acc[1][c], 0, 0, 0);
        }
    }
}

// ACT: 0 none, 1 sigmoid, 2 relu
template<int NC16, int ACT>
__device__ __forceinline__ void act_store_lds(_Float16* D, int ldd, f32x4 (&acc)[2][8],
        const float* bias, int ln, int q, int wid){
    #pragma unroll
    for (int r = 0; r < 2; ++r){
        int rowb = wid*32 + r*16 + q*4;
        #pragma unroll
        for (int c = 0; c < NC16; ++c){
            int col = c*16 + ln;
            float bv = bias ? bias[col] : 0.0f;
            #pragma unroll
            for (int i2 = 0; i2 < 4; ++i2){
                float v = acc[r][c][i2] + bv;
                if (ACT == 1) v = sigm(v);
                else if (ACT == 2) v = fmaxf(v, 0.0f);
                D[(size_t)(rowb + i2)*ldd + col] = (_Float16)v;
            }
        }
    }
}

__device__ __forceinline__ void stage_w(const _Float16* Wg, _Float16* Wl, int ldw,
                                        int C, int K, int tid){
    int kq = K/8, tot = C*kq;
    for (int i = tid; i < tot; i += 256){
        int r = i/kq, s = i%kq;
        *(f16x8*)&Wl[(size_t)r*ldw + s*8] = *(const f16x8*)&Wg[(size_t)r*K + s*8];
    }
}

// ================= fused input layer: g = (sigmoid(x@Win+bin)) @ Wgcn =================
__global__ __launch_bounds__(256,1) void fused_input_k(const float* __restrict__ x,
        const _Float16* __restrict__ WtIN, const float* __restrict__ b_in,
        const _Float16* __restrict__ WtGCN, _Float16* __restrict__ gOut, int nrows){
    __shared__ __align__(16) _Float16 Ax[128*40];
    __shared__ __align__(16) _Float16 Hl[128*136];
    __shared__ __align__(16) _Float16 Wi[128*40];
    __shared__ __align__(16) _Float16 Wg[128*136];
    int tid = threadIdx.x, lane = tid & 63, wid = tid >> 6;
    int ln = lane & 15, q = lane >> 4;
    int row0 = blockIdx.x * 128;
    for (int i = tid; i < 512; i += 256){
        int r = i >> 2, s = i & 3;
        f16x8 v = {};
        if (row0 + r < nrows){
            const float* xs = &x[(size_t)(row0+r)*DIN + s*8];
            float4 u0 = *(const float4*)xs, u1 = *(const float4*)(xs+4);
            v[0]=(_Float16)u0.x; v[1]=(_Float16)u0.y; v[2]=(_Float16)u0.z; v[3]=(_Float16)u0.w;
            v[4]=(_Float16)u1.x; v[5]=(_Float16)u1.y; v[6]=(_Float16)u1.z; v[7]=(_Float16)u1.w;
        }
        *(f16x8*)&Ax[r*40 + s*8] = v;
        *(f16x8*)&Wi[r*40 + s*8] = *(const f16x8*)&WtIN[(size_t)r*32 + s*8];
    }
    for (int i = tid; i < 2048; i += 256){
        int r = i >> 4, s = i & 15;
        *(f16x8*)&Wg[r*136 + s*8] = *(const f16x8*)&WtGCN[(size_t)r*128 + s*8];
    }
    __syncthreads();
    f32x4 acc[2][8];
    mfma_ldsmm<32,8,true>(Ax, 40, Wi, 40, acc, ln, q, wid);
    act_store_lds<8,1>(Hl, 136, acc, b_in, ln, q, wid);
    __syncthreads();
    mfma_ldsmm<128,8,true>(Hl, 136, Wg, 136, acc, ln, q, wid);
    #pragma unroll
    for (int r = 0; r < 2; ++r){
        int rowb = row0 + wid*32 + r*16 + q*4;
        #pragma unroll
        for (int c = 0; c < 8; ++c){
            int col = c*16 + ln;
            #pragma unroll
            for (int i2 = 0; i2 < 4; ++i2){
                int row = rowb + i2;
                if (row < nrows) gOut[(size_t)row*DL + col] = (_Float16)acc[r][c][i2];
            }
        }
    }
}

// ================= GCN aggregation (fp16 feats, fp32 accum, unroll-4) =================
__global__ __launch_bounds__(256) void gcn_agg_h(const _Float16* __restrict__ g,
        _Float16* __restrict__ out, const int* __restrict__ rowptr,
        const int* __restrict__ csr_src, const float* __restrict__ dinv,
        const float* __restrict__ bgcn, int N){
    int t = threadIdx.x;
    int node = blockIdx.x*16 + (t >> 4);
    int f = (t & 15)*8;
    if (node >= N) return;
    float dv = dinv[node];
    float sn = dv*dv;
    f16x8 sv = *(const f16x8*)&g[(size_t)node*DL + f];
    float acc[8];
    #pragma unroll
    for (int j = 0; j < 8; ++j) acc[j] = (float)sv[j]*sn + bgcn[f+j];
    int e = rowptr[node], e1 = rowptr[node+1];
    for (; e + 4 <= e1; e += 4){
        int s0 = csr_src[e], s1 = csr_src[e+1], s2 = csr_src[e+2], s3 = csr_src[e+3];
        float w0 = dinv[s0]*dv, w1 = dinv[s1]*dv, w2 = dinv[s2]*dv, w3 = dinv[s3]*dv;
        f16x8 n0 = *(const f16x8*)&g[(size_t)s0*DL + f];
        f16x8 n1 = *(const f16x8*)&g[(size_t)s1*DL + f];
        f16x8 n2 = *(const f16x8*)&g[(size_t)s2*DL + f];
        f16x8 n3 = *(const f16x8*)&g[(size_t)s3*DL + f];
        #pragma unroll
        for (int j = 0; j < 8; ++j)
            acc[j] += (float)n0[j]*w0 + (float)n1[j]*w1 + (float)n2[j]*w2 + (float)n3[j]*w3;
    }
    for (; e < e1; ++e){
        int s = csr_src[e];
        float w = dinv[s]*dv;
        f16x8 nv = *(const f16x8*)&g[(size_t)s*DL + f];
        #pragma unroll
        for (int j = 0; j < 8; ++j) acc[j] += (float)nv[j]*w;
    }
    f16x8 o;
    #pragma unroll
    for (int j = 0; j < 8; ++j) o[j] = (_Float16)acc[j];
    *(f16x8*)&out[(size_t)node*DL + f] = o;
}

// ================= fused hop v2: round-3 codegen shape + 68 KB LDS ===================
// 256 threads, wave owns 32 rows of the 128-row tile. Single in-place act buffer
// (each wave reads/writes only its own rows; same-wave LDS ops are ordered) +
// single coop-staged W buffer. std*eps buffered as packed f16 vectors (16 VGPRs)
// instead of a second f32 accumulator (64 VGPRs) -> fits under the 128-VGPR cap
// that (256,2) imposes, giving 2 blocks/CU (rounds 5-7 spilled at this cap with
// the 16-row shape; round 3 proved this 32-row helper shape compiles lean).
template<int LAST>
__global__ __launch_bounds__(256,2) void hop2_k(const _Float16* __restrict__ g2,
        const _Float16* __restrict__ Wt8, const float* __restrict__ b_enc,
        const float* __restrict__ b_mu, const float* __restrict__ b_std,
        const float* __restrict__ eps_i, _Float16* __restrict__ gOut,
        float* __restrict__ muOut, float* __restrict__ stdOut,
        _Float16* __restrict__ hOut, int nrows){
    __shared__ __align__(16) _Float16 Act[128*136];
    __shared__ __align__(16) _Float16 Wb[128*136];
    int tid = threadIdx.x, lane = tid & 63, wid = tid >> 6;
    int ln = lane & 15, q = lane >> 4;
    int row0 = blockIdx.x * 128;
    // stage act tile (cooperative)
    for (int i = tid; i < 2048; i += 256){
        int r = i >> 4, s = i & 15;
        f16x8 v = {};
        if (row0 + r < nrows) v = *(const f16x8*)&g2[(size_t)(row0+r)*DL + s*8];
        *(f16x8*)&Act[r*136 + s*8] = v;
    }
    f32x4 acc[2][8];
    auto stageW = [&](int m){
        __syncthreads();   // prior reads of Wb (and initial act stage) complete
        stage_w(Wt8 + (size_t)m*16384, Wb, 136, 128, 128, tid);
        __syncthreads();
    };
    // 5 encoder layers (sigmoid), in-place
    #pragma unroll 1
    for (int j = 0; j < 5; ++j){
        stageW(1+j);
        mfma_ldsmm<128,8,true>(Act, 136, Wb, 136, acc, ln, q, wid);
        act_store_lds<8,1>(Act, 136, acc, b_enc + j*DL, ln, q, wid);
    }
    // std pass: se = std*eps buffered as packed f16 (stdOut written directly if LAST)
    stageW(7);
    mfma_ldsmm<128,8,true>(Act, 136, Wb, 136, acc, ln, q, wid);
    f16x8 se[2][4];
    #pragma unroll
    for (int r = 0; r < 2; ++r){
        int rowb = row0 + wid*32 + r*16 + q*4;
        #pragma unroll
        for (int c = 0; c < 8; ++c){
            int col = c*16 + ln;
            float bs = b_std[col];
            #pragma unroll
            for (int i2 = 0; i2 < 4; ++i2){
                int grow = rowb + i2;
                float s = softplus_(acc[r][c][i2] + bs - 5.0f);
                float ev = (grow < nrows) ? eps_i[(size_t)grow*DL + col] : 0.0f;
                int fi = c*4 + i2;
                se[r][fi>>3][fi&7] = (_Float16)(s*ev);
                if (LAST && grow < nrows) stdOut[(size_t)grow*DL + col] = s;
            }
        }
    }
    // mu pass: h = mu + se -> Act (own rows); mu/h -> global if LAST
    stageW(6);
    mfma_ldsmm<128,8,true>(Act, 136, Wb, 136, acc, ln, q, wid);
    #pragma unroll
    for (int r = 0; r < 2; ++r){
        int rowl = wid*32 + r*16 + q*4;
        #pragma unroll
        for (int c = 0; c < 8; ++c){
            int col = c*16 + ln;
            float bm = b_mu[col];
            #pragma unroll
            for (int i2 = 0; i2 < 4; ++i2){
                int grow = row0 + rowl + i2;
                float mv = acc[r][c][i2] + bm;
                int fi = c*4 + i2;
                float hv = mv + (float)se[r][fi>>3][fi&7];
                Act[(size_t)(rowl + i2)*136 + col] = (_Float16)hv;
                if (LAST && grow < nrows){
                    muOut[(size_t)grow*DL + col] = mv;
                    hOut[(size_t)grow*DL + col] = (_Float16)hv;
                }
            }
        }
    }
    if (!LAST){
        // g = h @ Wgcn -> global
        stageW(0);
        mfma_ldsmm<128,8,true>(Act, 136, Wb, 136, acc, ln, q, wid);
        #pragma unroll
        for (int r = 0; r < 2; ++r){
            int rowb = row0 + wid*32 + r*16 + q*4;
            #pragma unroll
            for (int c = 0; c < 8; ++c){
                int col = c*16 + ln;
                #pragma unroll
                for (int i2 = 0; i2 < 4; ++i2){
                    int grow = rowb + i2;
                    if (grow < nrows) gOut[(size_t)grow*DL + col] = (_Float16)acc[r][c][i2];
                }
            }
        }
    }
}

// ================= fused decoder (round-3 style, LDS-staged weights) ==================
__global__ __launch_bounds__(256,1) void decoder_k(const _Float16* __restrict__ h,
        const _Float16* __restrict__ WtD0, const _Float16* __restrict__ WtD1,
        const _Float16* __restrict__ WtD2, const _Float16* __restrict__ WtD3,
        const _Float16* __restrict__ WtD4,
        const float* __restrict__ bd0, const float* __restrict__ bd1,
        const float* __restrict__ bd2, const float* __restrict__ bd3,
        const float* __restrict__ bd4, const float* __restrict__ Wo,
        const float* __restrict__ bo, const int* __restrict__ batch,
        float* __restrict__ sums, float* __restrict__ gcnt, int nrows){
    __shared__ __align__(16) _Float16 A[128*136];
    __shared__ __align__(16) _Float16 B[128*264];
    __shared__ __align__(16) _Float16 W[128*136];
    __shared__ float WoL[16*DOUT];
    __shared__ float boL[DOUT];
    int tid = threadIdx.x, lane = tid & 63, wid = tid >> 6;
    int ln = lane & 15, q = lane >> 4;
    int row0 = blockIdx.x * 128;
    for (int i = tid; i < 2048; i += 256){
        int r = i >> 4, s = i & 15;
        f16x8 v = {};
        if (row0 + r < nrows) v = *(const f16x8*)&h[(size_t)(row0+r)*DL + s*8];
        *(f16x8*)&A[r*136 + s*8] = v;
    }
    if (tid < 16*DOUT) WoL[tid] = Wo[tid];
    if (tid < DOUT) boL[tid] = bo[tid];
    f32x4 acc[2][8];
    // d0: 128 -> 256 (two col-halves)
    for (int ch = 0; ch < 2; ++ch){
        stage_w(WtD0 + (size_t)ch*128*128, W, 136, 128, 128, tid);
        __syncthreads();
        mfma_ldsmm<128,8,true>(A, 136, W, 136, acc, ln, q, wid);
        act_store_lds<8,2>(B + ch*128, 264, acc, bd0 + ch*128, ln, q, wid);
        __syncthreads();
    }
    // d1: 256 -> 128 (two K-halves, accumulate)
    for (int kh = 0; kh < 2; ++kh){
        for (int i = tid; i < 2048; i += 256){
            int r = i >> 4, s = i & 15;
            *(f16x8*)&W[r*136 + s*8] = *(const f16x8*)&WtD1[(size_t)r*256 + kh*128 + s*8];
        }
        __syncthreads();
        if (kh == 0) mfma_ldsmm<128,8,true >(B,       264, W, 136, acc, ln, q, wid);
        else         mfma_ldsmm<128,8,false>(B + 128, 264, W, 136, acc, ln, q, wid);
        __syncthreads();
    }
    act_store_lds<8,2>(A, 136, acc, bd1, ln, q, wid);
    __syncthreads();
    // d2: 128 -> 64
    stage_w(WtD2, W, 136, 64, 128, tid);
    __syncthreads();
    mfma_ldsmm<128,4,true>(A, 136, W, 136, acc, ln, q, wid);
    act_store_lds<4,2>(B, 264, acc, bd2, ln, q, wid);
    __syncthreads();
    // d3: 64 -> 32
    stage_w(WtD3, W, 136, 32, 64, tid);
    __syncthreads();
    mfma_ldsmm<64,2,true>(B, 264, W, 136, acc, ln, q, wid);
    act_store_lds<2,2>(A, 136, acc, bd3, ln, q, wid);
    __syncthreads();
    // d4: 32 -> 16
    stage_w(WtD4, W, 136, 16, 32, tid);
    __syncthreads();
    mfma_ldsmm<32,1,true>(A, 136, W, 136, acc, ln, q, wid);
    act_store_lds<1,2>(B, 264, acc, bd4, ln, q, wid);
    __syncthreads();
    // final 16 -> 10 sigmoid + mean-pool
    int node = row0 + tid;
    bool valid = (tid < 128) && (node < nrows);
    float yp[DOUT];
    int b = -1;
    if (valid){
        float dd[16];
        #pragma unroll
        for (int k = 0; k < 16; ++k) dd[k] = (float)B[(size_t)tid*264 + k];
        #pragma unroll
        for (int o = 0; o < DOUT; ++o){
            float a2 = boL[o];
            #pragma unroll
            for (int k = 0; k < 16; ++k) a2 += dd[k]*WoL[k*DOUT + o];
            yp[o] = sigm(a2);
        }
        b = batch[node];
    }
    int b0 = __builtin_amdgcn_readfirstlane(b);
    unsigned long long m = __ballot(b == b0);
    if (m == ~0ull && b0 >= 0){
        #pragma unroll
        for (int o = 0; o < DOUT; ++o){
            float v = yp[o];
            for (int off = 32; off > 0; off >>= 1) v += __shfl_xor(v, off);
            if ((tid & 63) == 0) atomicAdd(&sums[b0*DOUT + o], v);
        }
        if ((tid & 63) == 0) atomicAdd(&gcnt[b0], 64.0f);
    } else if (valid){
        #pragma unroll
        for (int o = 0; o < DOUT; ++o) atomicAdd(&sums[b*DOUT + o], yp[o]);
        atomicAdd(&gcnt[b], 1.0f);
    }
}

__global__ void divide_k(float* __restrict__ out, const float* __restrict__ gcnt, int n){
    int i = blockIdx.x*256 + threadIdx.x;
    if (i < n) out[i] = out[i] / fmaxf(gcnt[i/DOUT], 1.0f);
}

__global__ void copy_k(const float* __restrict__ src, float* __restrict__ dst, int n){
    int i = blockIdx.x*256 + threadIdx.x;
    if (i < n) dst[i] = src[i];
}

extern "C" void kernel_launch(void* const* d_in, const int* in_sizes, int n_in,
                              void* d_out, int out_size, void* d_ws, size_t ws_size,
                              hipStream_t stream) {
    const float* x     = (const float*)d_in[0];
    const int*   ei    = (const int*)d_in[1];
    const int*   batch = (const int*)d_in[2];
    const float* y     = (const float*)d_in[3];
    const float* eps   = (const float*)d_in[4];
    const float* W_in  = (const float*)d_in[5];
    const float* b_in  = (const float*)d_in[6];
    const float* W_gcn = (const float*)d_in[7];
    const float* b_gcn = (const float*)d_in[8];
    const float* W_enc = (const float*)d_in[9];
    const float* b_enc = (const float*)d_in[10];
    const float* W_mu  = (const float*)d_in[11];
    const float* b_mu  = (const float*)d_in[12];
    const float* W_std = (const float*)d_in[13];
    const float* b_std = (const float*)d_in[14];
    const float* Wd0 = (const float*)d_in[15]; const float* bd0 = (const float*)d_in[16];
    const float* Wd1 = (const float*)d_in[17]; const float* bd1 = (const float*)d_in[18];
    const float* Wd2 = (const float*)d_in[19]; const float* bd2 = (const float*)d_in[20];
    const float* Wd3 = (const float*)d_in[21]; const float* bd3 = (const float*)d_in[22];
    const float* Wd4 = (const float*)d_in[23]; const float* bd4 = (const float*)d_in[24];
    const float* Wo  = (const float*)d_in[25]; const float* bo  = (const float*)d_in[26];

    const int N = in_sizes[2];
    const int E = in_sizes[1]/2;
    const int G = in_sizes[3]/DOUT;
    const int KHOP = in_sizes[4] / (N*DL);   // = 3
    const size_t NN = (size_t)N*DL;

    char* p = (char*)d_ws;
    auto take = [&p](size_t bytes) -> char* {
        char* r = p; p += (bytes + 255) & ~(size_t)255; return r;
    };
    _Float16* hG  = (_Float16*)take(NN*2);
    _Float16* hG2 = (_Float16*)take(NN*2);
    _Float16* hH  = (_Float16*)take(NN*2);
    float* dinv  = (float*)take((size_t)N*4);
    float* gcnt  = (float*)take((size_t)G*4);
    int* cnt     = (int*)take((size_t)N*4);
    int* rowptr  = (int*)take((size_t)(N+1)*4);
    int* cursor  = (int*)take((size_t)N*4);
    int* csr_src = (int*)take((size_t)E*4);
    int* bsum    = (int*)take(1024*4);
    _Float16* Wt8  = (_Float16*)take((size_t)8*DL*DL*2);  // gcn, enc0..4, mu, std
    _Float16* WtIN = (_Float16*)take((size_t)DL*DIN*2);
    _Float16* WtD0 = (_Float16*)take((size_t)256*128*2);
    _Float16* WtD1 = (_Float16*)take((size_t)128*256*2);
    _Float16* WtD2 = (_Float16*)take((size_t)64*128*2);
    _Float16* WtD3 = (_Float16*)take((size_t)32*64*2);
    _Float16* WtD4 = (_Float16*)take((size_t)16*32*2);

    float* out_ypred = (float*)d_out;                    // [G,10]
    float* out_mu    = out_ypred + (size_t)G*DOUT;       // [N,128]
    float* out_std   = out_mu + NN;                      // [N,128]
    float* out_y     = out_std + NN;                     // [G,10]

    hipMemsetAsync(cnt, 0, sizeof(int)*N, stream);
    hipMemsetAsync(out_ypred, 0, sizeof(float)*G*DOUT, stream);
    hipMemsetAsync(gcnt, 0, sizeof(float)*G, stream);

    int gE = (E + 255)/256, gN = (N + 255)/256;
    int nb = gN;

    count_edges_k<<<gE, 256, 0, stream>>>(ei, cnt, E);
    dinv_k<<<gN, 256, 0, stream>>>(cnt, dinv, N);
    block_sum_k<<<nb, 256, 0, stream>>>(cnt, bsum, N);
    scan_bsum_k<<<1, 1024, 0, stream>>>(bsum, nb);
    block_scan_k<<<nb, 256, 0, stream>>>(cnt, bsum, cursor, rowptr, N);
    place_edges_k<<<gE, 256, 0, stream>>>(ei, cursor, csr_src, E);

    WPA14 wa;
    wa.a[0]  = { W_in,  WtIN, DIN, DL };
    wa.a[1]  = { W_gcn, Wt8,  DL, DL };
    for (int j = 0; j < 5; ++j) wa.a[2+j] = { W_enc + (size_t)j*DL*DL, Wt8 + (size_t)(1+j)*DL*DL, DL, DL };
    wa.a[7]  = { W_mu,  Wt8 + (size_t)6*DL*DL, DL, DL };
    wa.a[8]  = { W_std, Wt8 + (size_t)7*DL*DL, DL, DL };
    wa.a[9]  = { Wd0, WtD0, 128, 256 };
    wa.a[10] = { Wd1, WtD1, 256, 128 };
    wa.a[11] = { Wd2, WtD2, 128, 64 };
    wa.a[12] = { Wd3, WtD3, 64, 32 };
    wa.a[13] = { Wd4, WtD4, 32, 16 };
    wprep_all_k<<<dim3(128, 14), 256, 0, stream>>>(wa);

    int ntile = (N + 127)/128;
    fused_input_k<<<ntile, 256, 0, stream>>>(x, WtIN, b_in, Wt8, hG, N);

    for (int i = 0; i < KHOP; ++i){
        gcn_agg_h<<<(N+15)/16, 256, 0, stream>>>(hG, hG2, rowptr, csr_src, dinv, b_gcn, N);
        const float* eps_i = eps + (size_t)i*NN;
        if (i == KHOP-1)
            hop2_k<1><<<ntile, 256, 0, stream>>>(hG2, Wt8, b_enc, b_mu, b_std, eps_i,
                                                 nullptr, out_mu, out_std, hH, N);
        else
            hop2_k<0><<<ntile, 256, 0, stream>>>(hG2, Wt8, b_enc, b_mu, b_std, eps_i,
                                                 hG, nullptr, nullptr, nullptr, N);
    }

    decoder_k<<<ntile, 256, 0, stream>>>(hH, WtD0, WtD1, WtD2, WtD3, WtD4,
                                         bd0, bd1, bd2, bd3, bd4, Wo, bo,
                                         batch, out_ypred, gcnt, N);
    divide_k<<<(G*DOUT+255)/256, 256, 0, stream>>>(out_ypred, gcnt, G*DOUT);
    copy_k<<<(G*DOUT+255)/256, 256, 0, stream>>>(y, out_y, G*DOUT);
}

// Round 9
// 776.258 us; speedup vs baseline: 1.7559x; 1.0223x over previous
//
#include <hip/hip_runtime.h>
#include <math.h>

#define DIN 32
#define DL 128
#define DOUT 10

typedef _Float16 f16x8 __attribute__((ext_vector_type(8)));
typedef float f32x4 __attribute__((ext_vector_type(4)));

__device__ __forceinline__ float sigm(float x){ return 1.0f/(1.0f+expf(-x)); }
__device__ __forceinline__ float softplus_(float x){ return fmaxf(x,0.0f) + log1pf(expf(-fabsf(x))); }

// ================= graph preprocessing =================
__global__ void count_edges_k(const int* __restrict__ ei, int* __restrict__ cnt, int E){
    int e = blockIdx.x*256 + threadIdx.x;
    if (e < E) atomicAdd(&cnt[ei[E + e]], 1);   // dst = ei[1][e]
}

__global__ void dinv_k(const int* __restrict__ cnt, float* __restrict__ dinv, int N){
    int i = blockIdx.x*256 + threadIdx.x;
    if (i < N) dinv[i] = rsqrtf((float)cnt[i] + 1.0f);
}

__global__ void block_sum_k(const int* __restrict__ cnt, int* __restrict__ bsum, int n){
    __shared__ int ws_[4];
    int tid = threadIdx.x;
    int i = blockIdx.x*256 + tid;
    int v = (i < n) ? cnt[i] : 0;
    #pragma unroll
    for (int off = 32; off > 0; off >>= 1) v += __shfl_xor(v, off);
    if ((tid & 63) == 0) ws_[tid >> 6] = v;
    __syncthreads();
    if (tid == 0) bsum[blockIdx.x] = ws_[0] + ws_[1] + ws_[2] + ws_[3];
}

__global__ void scan_bsum_k(int* __restrict__ bsum, int nb){
    __shared__ int tmp[1024];
    int tid = threadIdx.x;
    int v = (tid < nb) ? bsum[tid] : 0;
    tmp[tid] = v; __syncthreads();
    for (int off = 1; off < 1024; off <<= 1){
        int t = (tid >= off) ? tmp[tid-off] : 0;
        __syncthreads();
        tmp[tid] += t;
        __syncthreads();
    }
    if (tid < nb) bsum[tid] = tmp[tid] - v;   // exclusive
}

__global__ void block_scan_k(const int* __restrict__ cnt, const int* __restrict__ bexcl,
                             int* __restrict__ cursor, int* __restrict__ rowptr, int n){
    __shared__ int tmp[256];
    int tid = threadIdx.x;
    int i = blockIdx.x*256 + tid;
    int v = (i < n) ? cnt[i] : 0;
    tmp[tid] = v; __syncthreads();
    for (int off = 1; off < 256; off <<= 1){
        int t = (tid >= off) ? tmp[tid-off] : 0;
        __syncthreads();
        tmp[tid] += t;
        __syncthreads();
    }
    int excl = bexcl[blockIdx.x] + tmp[tid] - v;
    if (i < n){ cursor[i] = excl; rowptr[i+1] = excl + v; }
    if (i == 0) rowptr[0] = 0;
}

__global__ void place_edges_k(const int* __restrict__ ei, int* __restrict__ cursor,
                              int* __restrict__ csr_src, int E){
    int e = blockIdx.x*256 + threadIdx.x;
    if (e < E){
        int s = ei[e], d = ei[E + e];
        csr_src[atomicAdd(&cursor[d], 1)] = s;
    }
}

// ================= weight prep: fp32 [K][C] -> fp16 transposed [C][K] =================
struct WPA { const float* s; _Float16* d; int K; int C; };
struct WPA14 { WPA a[14]; };
__global__ void wprep_all_k(WPA14 args){
    WPA w = args.a[blockIdx.y];
    int idx = blockIdx.x*256 + threadIdx.x;
    if (idx < w.K*w.C){ int k = idx / w.C, c = idx % w.C; w.d[(size_t)c*w.K + k] = (_Float16)w.s[idx]; }
}

// ================= MFMA helpers =================
template<int K, int NC16, bool ZERO>
__device__ __forceinline__ void mfma_ldsmm(const _Float16* As, int lda,
        const _Float16* Ws, int ldw, f32x4 (&acc)[2][8], int ln, int q, int wid){
    if (ZERO){
        #pragma unroll
        for (int r = 0; r < 2; ++r)
            #pragma unroll
            for (int c = 0; c < 8; ++c) acc[r][c] = (f32x4){0.f,0.f,0.f,0.f};
    }
    #pragma unroll
    for (int kk = 0; kk < K/32; ++kk){
        int ko = kk*32 + q*8;
        f16x8 a0 = *(const f16x8*)&As[(size_t)(wid*32 + ln)*lda + ko];
        f16x8 a1 = *(const f16x8*)&As[(size_t)(wid*32 + 16 + ln)*lda + ko];
        #pragma unroll
        for (int c = 0; c < NC16; ++c){
            f16x8 b = *(const f16x8*)&Ws[(size_t)(c*16 + ln)*ldw + ko];
            acc[0][c] = __builtin_amdgcn_mfma_f32_16x16x32_f16(a0, b, acc[0][c], 0, 0, 0);
            acc[1][c] = __builtin_amdgcn_mfma_f32_16x16x32_f16(a1, b, acc[1][c], 0, 0, 0);
        }
    }
}

// ACT: 0 none, 1 sigmoid, 2 relu
template<int NC16, int ACT>
__device__ __forceinline__ void act_store_lds(_Float16* D, int ldd, f32x4 (&acc)[2][8],
        const float* bias, int ln, int q, int wid){
    #pragma unroll
    for (int r = 0; r < 2; ++r){
        int rowb = wid*32 + r*16 + q*4;
        #pragma unroll
        for (int c = 0; c < NC16; ++c){
            int col = c*16 + ln;
            float bv = bias ? bias[col] : 0.0f;
            #pragma unroll
            for (int i2 = 0; i2 < 4; ++i2){
                float v = acc[r][c][i2] + bv;
                if (ACT == 1) v = sigm(v);
                else if (ACT == 2) v = fmaxf(v, 0.0f);
                D[(size_t)(rowb + i2)*ldd + col] = (_Float16)v;
            }
        }
    }
}

// 64-row-tile GEMM: 4 waves, wave owns 16 rows; B from LDS W buffer (stride 136)
template<int K, int NC16, bool ZERO>
__device__ __forceinline__ void gemm64(const _Float16* As, const _Float16* Ws,
        f32x4 (&acc)[NC16], int ln, int q, int wid){
    if (ZERO){
        #pragma unroll
        for (int c = 0; c < NC16; ++c) acc[c] = (f32x4){0.f,0.f,0.f,0.f};
    }
    #pragma unroll
    for (int kk = 0; kk < K/32; ++kk){
        int ko = kk*32 + q*8;
        f16x8 a = *(const f16x8*)&As[(size_t)(wid*16 + ln)*136 + ko];
        #pragma unroll
        for (int c = 0; c < NC16; ++c){
            f16x8 b = *(const f16x8*)&Ws[(size_t)(c*16 + ln)*136 + ko];
            acc[c] = __builtin_amdgcn_mfma_f32_16x16x32_f16(a, b, acc[c], 0, 0, 0);
        }
    }
}

template<int NC16>
__device__ __forceinline__ void relu_st64(_Float16* D, f32x4 (&acc)[NC16],
        const float* bias, int ln, int q, int wid){
    int rowb = wid*16 + q*4;
    #pragma unroll
    for (int c = 0; c < NC16; ++c){
        int col = c*16 + ln;
        float bv = bias[col];
        #pragma unroll
        for (int i2 = 0; i2 < 4; ++i2)
            D[(size_t)(rowb + i2)*136 + col] = (_Float16)fmaxf(acc[c][i2] + bv, 0.0f);
    }
}

// stage weight tile [C cols][K k] from global (row stride srcStride, k offset kOff) -> LDS stride 136
__device__ __forceinline__ void stage_w2(const _Float16* Wg, int srcStride, int kOff,
                                         int C, int K, _Float16* Wl, int tid){
    int kq = K/8, tot = C*kq;
    for (int i = tid; i < tot; i += 256){
        int r = i/kq, s = i%kq;
        *(f16x8*)&Wl[(size_t)r*136 + s*8] = *(const f16x8*)&Wg[(size_t)r*srcStride + kOff + s*8];
    }
}

// 128x128 fp16 weight prefetch: 2048 16B granules, 8 per thread (256 thr)
__device__ __forceinline__ void pf_load_w(const _Float16* Wg, f16x8 (&pf)[8], int tid){
    #pragma unroll
    for (int i = 0; i < 8; ++i) pf[i] = *(const f16x8*)&Wg[(size_t)(tid + i*256)*8];
}
__device__ __forceinline__ void pf_store_w(_Float16* Wl, f16x8 (&pf)[8], int tid){
    #pragma unroll
    for (int i = 0; i < 8; ++i){
        int g = tid + i*256; int r = g >> 4, s = g & 15;
        *(f16x8*)&Wl[(size_t)r*136 + s*8] = pf[i];
    }
}

// ================= fused input layer: g = (sigmoid(x@Win+bin)) @ Wgcn =================
__global__ __launch_bounds__(256,1) void fused_input_k(const float* __restrict__ x,
        const _Float16* __restrict__ WtIN, const float* __restrict__ b_in,
        const _Float16* __restrict__ WtGCN, _Float16* __restrict__ gOut, int nrows){
    __shared__ __align__(16) _Float16 Ax[128*40];
    __shared__ __align__(16) _Float16 Hl[128*136];
    __shared__ __align__(16) _Float16 Wi[128*40];
    __shared__ __align__(16) _Float16 Wg[128*136];
    int tid = threadIdx.x, lane = tid & 63, wid = tid >> 6;
    int ln = lane & 15, q = lane >> 4;
    int row0 = blockIdx.x * 128;
    for (int i = tid; i < 512; i += 256){
        int r = i >> 2, s = i & 3;
        f16x8 v = {};
        if (row0 + r < nrows){
            const float* xs = &x[(size_t)(row0+r)*DIN + s*8];
            float4 u0 = *(const float4*)xs, u1 = *(const float4*)(xs+4);
            v[0]=(_Float16)u0.x; v[1]=(_Float16)u0.y; v[2]=(_Float16)u0.z; v[3]=(_Float16)u0.w;
            v[4]=(_Float16)u1.x; v[5]=(_Float16)u1.y; v[6]=(_Float16)u1.z; v[7]=(_Float16)u1.w;
        }
        *(f16x8*)&Ax[r*40 + s*8] = v;
        *(f16x8*)&Wi[r*40 + s*8] = *(const f16x8*)&WtIN[(size_t)r*32 + s*8];
    }
    for (int i = tid; i < 2048; i += 256){
        int r = i >> 4, s = i & 15;
        *(f16x8*)&Wg[r*136 + s*8] = *(const f16x8*)&WtGCN[(size_t)r*128 + s*8];
    }
    __syncthreads();
    f32x4 acc[2][8];
    mfma_ldsmm<32,8,true>(Ax, 40, Wi, 40, acc, ln, q, wid);
    act_store_lds<8,1>(Hl, 136, acc, b_in, ln, q, wid);
    __syncthreads();
    mfma_ldsmm<128,8,true>(Hl, 136, Wg, 136, acc, ln, q, wid);
    #pragma unroll
    for (int r = 0; r < 2; ++r){
        int rowb = row0 + wid*32 + r*16 + q*4;
        #pragma unroll
        for (int c = 0; c < 8; ++c){
            int col = c*16 + ln;
            #pragma unroll
            for (int i2 = 0; i2 < 4; ++i2){
                int row = rowb + i2;
                if (row < nrows) gOut[(size_t)row*DL + col] = (_Float16)acc[r][c][i2];
            }
        }
    }
}

// ================= GCN aggregation (fp16 feats, fp32 accum, unroll-4) =================
__global__ __launch_bounds__(256) void gcn_agg_h(const _Float16* __restrict__ g,
        _Float16* __restrict__ out, const int* __restrict__ rowptr,
        const int* __restrict__ csr_src, const float* __restrict__ dinv,
        const float* __restrict__ bgcn, int N){
    int t = threadIdx.x;
    int node = blockIdx.x*16 + (t >> 4);
    int f = (t & 15)*8;
    if (node >= N) return;
    float dv = dinv[node];
    float sn = dv*dv;
    f16x8 sv = *(const f16x8*)&g[(size_t)node*DL + f];
    float acc[8];
    #pragma unroll
    for (int j = 0; j < 8; ++j) acc[j] = (float)sv[j]*sn + bgcn[f+j];
    int e = rowptr[node], e1 = rowptr[node+1];
    for (; e + 4 <= e1; e += 4){
        int s0 = csr_src[e], s1 = csr_src[e+1], s2 = csr_src[e+2], s3 = csr_src[e+3];
        float w0 = dinv[s0]*dv, w1 = dinv[s1]*dv, w2 = dinv[s2]*dv, w3 = dinv[s3]*dv;
        f16x8 n0 = *(const f16x8*)&g[(size_t)s0*DL + f];
        f16x8 n1 = *(const f16x8*)&g[(size_t)s1*DL + f];
        f16x8 n2 = *(const f16x8*)&g[(size_t)s2*DL + f];
        f16x8 n3 = *(const f16x8*)&g[(size_t)s3*DL + f];
        #pragma unroll
        for (int j = 0; j < 8; ++j)
            acc[j] += (float)n0[j]*w0 + (float)n1[j]*w1 + (float)n2[j]*w2 + (float)n3[j]*w3;
    }
    for (; e < e1; ++e){
        int s = csr_src[e];
        float w = dinv[s]*dv;
        f16x8 nv = *(const f16x8*)&g[(size_t)s*DL + f];
        #pragma unroll
        for (int j = 0; j < 8; ++j) acc[j] += (float)nv[j]*w;
    }
    f16x8 o;
    #pragma unroll
    for (int j = 0; j < 8; ++j) o[j] = (_Float16)acc[j];
    *(f16x8*)&out[(size_t)node*DL + f] = o;
}

// ================= fused hop v3: 68 KB LDS + register W-prefetch =====================
// 256 threads, wave owns 32 rows; in-place act buffer (same-wave LDS ordering);
// next layer's W prefetched into regs while current GEMM runs -> global latency
// hidden behind MFMA; barriers only around the reg->LDS W commit.
template<int LAST>
__global__ __launch_bounds__(256,2) void hop2_k(const _Float16* __restrict__ g2,
        const _Float16* __restrict__ Wt8, const float* __restrict__ b_enc,
        const float* __restrict__ b_mu, const float* __restrict__ b_std,
        const float* __restrict__ eps_i, _Float16* __restrict__ gOut,
        float* __restrict__ muOut, float* __restrict__ stdOut,
        _Float16* __restrict__ hOut, int nrows){
    __shared__ __align__(16) _Float16 Act[128*136];
    __shared__ __align__(16) _Float16 Wb[128*136];
    int tid = threadIdx.x, lane = tid & 63, wid = tid >> 6;
    int ln = lane & 15, q = lane >> 4;
    int row0 = blockIdx.x * 128;
    f16x8 pf[8];
    pf_load_w(Wt8 + (size_t)1*16384, pf, tid);    // enc0
    // stage act tile (cooperative; overlaps pf loads)
    for (int i = tid; i < 2048; i += 256){
        int r = i >> 4, s = i & 15;
        f16x8 v = {};
        if (row0 + r < nrows) v = *(const f16x8*)&g2[(size_t)(row0+r)*DL + s*8];
        *(f16x8*)&Act[r*136 + s*8] = v;
    }
    pf_store_w(Wb, pf, tid);
    __syncthreads();
    f32x4 acc[2][8];
    // 5 encoder layers (sigmoid), in-place; prefetch next W during GEMM
    #pragma unroll 1
    for (int j = 0; j < 5; ++j){
        pf_load_w(Wt8 + (size_t)((j < 4) ? (2+j) : 7)*16384, pf, tid);   // enc j+1 or std
        mfma_ldsmm<128,8,true>(Act, 136, Wb, 136, acc, ln, q, wid);
        __syncthreads();                 // all waves done reading Wb
        pf_store_w(Wb, pf, tid);
        act_store_lds<8,1>(Act, 136, acc, b_enc + j*DL, ln, q, wid);  // own rows
        __syncthreads();                 // Wb commit visible
    }
    // std pass; prefetch mu
    pf_load_w(Wt8 + (size_t)6*16384, pf, tid);
    mfma_ldsmm<128,8,true>(Act, 136, Wb, 136, acc, ln, q, wid);
    __syncthreads();
    pf_store_w(Wb, pf, tid);
    f16x8 se[2][4];
    #pragma unroll
    for (int r = 0; r < 2; ++r){
        int rowb = row0 + wid*32 + r*16 + q*4;
        #pragma unroll
        for (int c = 0; c < 8; ++c){
            int col = c*16 + ln;
            float bs = b_std[col];
            #pragma unroll
            for (int i2 = 0; i2 < 4; ++i2){
                int grow = rowb + i2;
                float s = softplus_(acc[r][c][i2] + bs - 5.0f);
                float ev = (grow < nrows) ? eps_i[(size_t)grow*DL + col] : 0.0f;
                int fi = c*4 + i2;
                se[r][fi>>3][fi&7] = (_Float16)(s*ev);
                if (LAST && grow < nrows) stdOut[(size_t)grow*DL + col] = s;
            }
        }
    }
    __syncthreads();
    // mu pass; prefetch gcn if needed
    if (!LAST) pf_load_w(Wt8, pf, tid);
    mfma_ldsmm<128,8,true>(Act, 136, Wb, 136, acc, ln, q, wid);
    if (LAST){
        #pragma unroll
        for (int r = 0; r < 2; ++r){
            int rowb = row0 + wid*32 + r*16 + q*4;
            #pragma unroll
            for (int c = 0; c < 8; ++c){
                int col = c*16 + ln;
                float bm = b_mu[col];
                #pragma unroll
                for (int i2 = 0; i2 < 4; ++i2){
                    int grow = rowb + i2;
                    if (grow < nrows){
                        float mv = acc[r][c][i2] + bm;
                        int fi = c*4 + i2;
                        muOut[(size_t)grow*DL + col] = mv;
                        hOut[(size_t)grow*DL + col] = (_Float16)(mv + (float)se[r][fi>>3][fi&7]);
                    }
                }
            }
        }
    } else {
        __syncthreads();
        pf_store_w(Wb, pf, tid);
        #pragma unroll
        for (int r = 0; r < 2; ++r){
            int rowl = wid*32 + r*16 + q*4;
            #pragma unroll
            for (int c = 0; c < 8; ++c){
                int col = c*16 + ln;
                float bm = b_mu[col];
                #pragma unroll
                for (int i2 = 0; i2 < 4; ++i2){
                    int fi = c*4 + i2;
                    float hv = acc[r][c][i2] + bm + (float)se[r][fi>>3][fi&7];
                    Act[(size_t)(rowl + i2)*136 + col] = (_Float16)hv;   // own rows
                }
            }
        }
        __syncthreads();
        mfma_ldsmm<128,8,true>(Act, 136, Wb, 136, acc, ln, q, wid);
        #pragma unroll
        for (int r = 0; r < 2; ++r){
            int rowb = row0 + wid*32 + r*16 + q*4;
            #pragma unroll
            for (int c = 0; c < 8; ++c){
                int col = c*16 + ln;
                #pragma unroll
                for (int i2 = 0; i2 < 4; ++i2){
                    int grow = rowb + i2;
                    if (grow < nrows) gOut[(size_t)grow*DL + col] = (_Float16)acc[r][c][i2];
                }
            }
        }
    }
}

// ================= fused decoder v2: 64-row tiles, 68 KB LDS, d0/d1 interleaved ======
// A,B = 17 KB act buffers; W = 34 KB. The 256-wide intermediate is never materialized:
// per 128-col half ch, B = relu(A@Wd0_ch) then acc1 += B @ Wd1[k-half ch].
// Wave owns 16 rows -> all act LDS traffic is same-wave ordered; barriers only for W.
__global__ __launch_bounds__(256,2) void decoder_k(const _Float16* __restrict__ h,
        const _Float16* __restrict__ WtD0, const _Float16* __restrict__ WtD1,
        const _Float16* __restrict__ WtD2, const _Float16* __restrict__ WtD3,
        const _Float16* __restrict__ WtD4,
        const float* __restrict__ bd0, const float* __restrict__ bd1,
        const float* __restrict__ bd2, const float* __restrict__ bd3,
        const float* __restrict__ bd4, const float* __restrict__ Wo,
        const float* __restrict__ bo, const int* __restrict__ batch,
        float* __restrict__ sums, float* __restrict__ gcnt, int nrows){
    __shared__ __align__(16) _Float16 A[64*136];
    __shared__ __align__(16) _Float16 B[64*136];
    __shared__ __align__(16) _Float16 W[128*136];
    __shared__ float WoL[16*DOUT];
    __shared__ float boL[DOUT];
    int tid = threadIdx.x, lane = tid & 63, wid = tid >> 6;
    int ln = lane & 15, q = lane >> 4;
    int row0 = blockIdx.x * 64;
    // stage h tile (64 rows)
    for (int i = tid; i < 1024; i += 256){
        int r = i >> 4, s = i & 15;
        f16x8 v = {};
        if (row0 + r < nrows) v = *(const f16x8*)&h[(size_t)(row0+r)*DL + s*8];
        *(f16x8*)&A[r*136 + s*8] = v;
    }
    if (tid < 16*DOUT) WoL[tid] = Wo[tid];
    if (tid < DOUT) boL[tid] = bo[tid];
    f32x4 acc0[8], acc1[8];
    // ---- d0/d1 interleaved over two halves ----
    #pragma unroll 1
    for (int ch = 0; ch < 2; ++ch){
        if (ch) __syncthreads();                         // done reading W (prev d1 gemm)
        stage_w2(WtD0 + (size_t)ch*128*128, 128, 0, 128, 128, W, tid);
        __syncthreads();
        gemm64<128,8,true>(A, W, acc0, ln, q, wid);
        relu_st64<8>(B, acc0, bd0 + ch*128, ln, q, wid); // own rows
        __syncthreads();                                 // done reading W (d0 gemm)
        stage_w2(WtD1, 256, ch*128, 128, 128, W, tid);
        __syncthreads();
        if (ch == 0) gemm64<128,8,true >(B, W, acc1, ln, q, wid);
        else         gemm64<128,8,false>(B, W, acc1, ln, q, wid);
    }
    relu_st64<8>(A, acc1, bd1, ln, q, wid);              // h dead; own rows
    __syncthreads();
    // ---- d2: 128 -> 64 ----
    stage_w2(WtD2, 128, 0, 64, 128, W, tid);
    __syncthreads();
    gemm64<128,4,true>(A, W, *(f32x4(*)[4])acc0, ln, q, wid);
    relu_st64<4>(B, *(f32x4(*)[4])acc0, bd2, ln, q, wid);
    __syncthreads();
    // ---- d3: 64 -> 32 ----
    stage_w2(WtD3, 64, 0, 32, 64, W, tid);
    __syncthreads();
    gemm64<64,2,true>(B, W, *(f32x4(*)[2])acc0, ln, q, wid);
    relu_st64<2>(A, *(f32x4(*)[2])acc0, bd3, ln, q, wid);
    __syncthreads();
    // ---- d4: 32 -> 16 ----
    stage_w2(WtD4, 32, 0, 16, 32, W, tid);
    __syncthreads();
    gemm64<32,1,true>(A, W, *(f32x4(*)[1])acc0, ln, q, wid);
    relu_st64<1>(B, *(f32x4(*)[1])acc0, bd4, ln, q, wid);
    __syncthreads();
    // ---- final 16 -> 10 sigmoid + mean-pool ----
    int node = row0 + tid;
    bool valid = (tid < 64) && (node < nrows);
    float yp[DOUT];
    int b = -1;
    if (valid){
        float dd[16];
        #pragma unroll
        for (int k = 0; k < 16; ++k) dd[k] = (float)B[(size_t)tid*136 + k];
        #pragma unroll
        for (int o = 0; o < DOUT; ++o){
            float a2 = boL[o];
            #pragma unroll
            for (int k = 0; k < 16; ++k) a2 += dd[k]*WoL[k*DOUT + o];
            yp[o] = sigm(a2);
        }
        b = batch[node];
    }
    int b0 = __builtin_amdgcn_readfirstlane(b);
    unsigned long long m = __ballot(b == b0);
    if (m == ~0ull && b0 >= 0){
        #pragma unroll
        for (int o = 0; o < DOUT; ++o){
            float v = yp[o];
            for (int off = 32; off > 0; off >>= 1) v += __shfl_xor(v, off);
            if ((tid & 63) == 0) atomicAdd(&sums[b0*DOUT + o], v);
        }
        if ((tid & 63) == 0) atomicAdd(&gcnt[b0], 64.0f);
    } else if (valid){
        #pragma unroll
        for (int o = 0; o < DOUT; ++o) atomicAdd(&sums[b*DOUT + o], yp[o]);
        atomicAdd(&gcnt[b], 1.0f);
    }
}

__global__ void divide_k(float* __restrict__ out, const float* __restrict__ gcnt, int n){
    int i = blockIdx.x*256 + threadIdx.x;
    if (i < n) out[i] = out[i] / fmaxf(gcnt[i/DOUT], 1.0f);
}

__global__ void copy_k(const float* __restrict__ src, float* __restrict__ dst, int n){
    int i = blockIdx.x*256 + threadIdx.x;
    if (i < n) dst[i] = src[i];
}

extern "C" void kernel_launch(void* const* d_in, const int* in_sizes, int n_in,
                              void* d_out, int out_size, void* d_ws, size_t ws_size,
                              hipStream_t stream) {
    const float* x     = (const float*)d_in[0];
    const int*   ei    = (const int*)d_in[1];
    const int*   batch = (const int*)d_in[2];
    const float* y     = (const float*)d_in[3];
    const float* eps   = (const float*)d_in[4];
    const float* W_in  = (const float*)d_in[5];
    const float* b_in  = (const float*)d_in[6];
    const float* W_gcn = (const float*)d_in[7];
    const float* b_gcn = (const float*)d_in[8];
    const float* W_enc = (const float*)d_in[9];
    const float* b_enc = (const float*)d_in[10];
    const float* W_mu  = (const float*)d_in[11];
    const float* b_mu  = (const float*)d_in[12];
    const float* W_std = (const float*)d_in[13];
    const float* b_std = (const float*)d_in[14];
    const float* Wd0 = (const float*)d_in[15]; const float* bd0 = (const float*)d_in[16];
    const float* Wd1 = (const float*)d_in[17]; const float* bd1 = (const float*)d_in[18];
    const float* Wd2 = (const float*)d_in[19]; const float* bd2 = (const float*)d_in[20];
    const float* Wd3 = (const float*)d_in[21]; const float* bd3 = (const float*)d_in[22];
    const float* Wd4 = (const float*)d_in[23]; const float* bd4 = (const float*)d_in[24];
    const float* Wo  = (const float*)d_in[25]; const float* bo  = (const float*)d_in[26];

    const int N = in_sizes[2];
    const int E = in_sizes[1]/2;
    const int G = in_sizes[3]/DOUT;
    const int KHOP = in_sizes[4] / (N*DL);   // = 3
    const size_t NN = (size_t)N*DL;

    char* p = (char*)d_ws;
    auto take = [&p](size_t bytes) -> char* {
        char* r = p; p += (bytes + 255) & ~(size_t)255; return r;
    };
    _Float16* hG  = (_Float16*)take(NN*2);
    _Float16* hG2 = (_Float16*)take(NN*2);
    _Float16* hH  = (_Float16*)take(NN*2);
    float* dinv  = (float*)take((size_t)N*4);
    float* gcnt  = (float*)take((size_t)G*4);
    int* cnt     = (int*)take((size_t)N*4);
    int* rowptr  = (int*)take((size_t)(N+1)*4);
    int* cursor  = (int*)take((size_t)N*4);
    int* csr_src = (int*)take((size_t)E*4);
    int* bsum    = (int*)take(1024*4);
    _Float16* Wt8  = (_Float16*)take((size_t)8*DL*DL*2);  // gcn, enc0..4, mu, std
    _Float16* WtIN = (_Float16*)take((size_t)DL*DIN*2);
    _Float16* WtD0 = (_Float16*)take((size_t)256*128*2);
    _Float16* WtD1 = (_Float16*)take((size_t)128*256*2);
    _Float16* WtD2 = (_Float16*)take((size_t)64*128*2);
    _Float16* WtD3 = (_Float16*)take((size_t)32*64*2);
    _Float16* WtD4 = (_Float16*)take((size_t)16*32*2);

    float* out_ypred = (float*)d_out;                    // [G,10]
    float* out_mu    = out_ypred + (size_t)G*DOUT;       // [N,128]
    float* out_std   = out_mu + NN;                      // [N,128]
    float* out_y     = out_std + NN;                     // [G,10]

    hipMemsetAsync(cnt, 0, sizeof(int)*N, stream);
    hipMemsetAsync(out_ypred, 0, sizeof(float)*G*DOUT, stream);
    hipMemsetAsync(gcnt, 0, sizeof(float)*G, stream);

    int gE = (E + 255)/256, gN = (N + 255)/256;
    int nb = gN;

    count_edges_k<<<gE, 256, 0, stream>>>(ei, cnt, E);
    dinv_k<<<gN, 256, 0, stream>>>(cnt, dinv, N);
    block_sum_k<<<nb, 256, 0, stream>>>(cnt, bsum, N);
    scan_bsum_k<<<1, 1024, 0, stream>>>(bsum, nb);
    block_scan_k<<<nb, 256, 0, stream>>>(cnt, bsum, cursor, rowptr, N);
    place_edges_k<<<gE, 256, 0, stream>>>(ei, cursor, csr_src, E);

    WPA14 wa;
    wa.a[0]  = { W_in,  WtIN, DIN, DL };
    wa.a[1]  = { W_gcn, Wt8,  DL, DL };
    for (int j = 0; j < 5; ++j) wa.a[2+j] = { W_enc + (size_t)j*DL*DL, Wt8 + (size_t)(1+j)*DL*DL, DL, DL };
    wa.a[7]  = { W_mu,  Wt8 + (size_t)6*DL*DL, DL, DL };
    wa.a[8]  = { W_std, Wt8 + (size_t)7*DL*DL, DL, DL };
    wa.a[9]  = { Wd0, WtD0, 128, 256 };
    wa.a[10] = { Wd1, WtD1, 256, 128 };
    wa.a[11] = { Wd2, WtD2, 128, 64 };
    wa.a[12] = { Wd3, WtD3, 64, 32 };
    wa.a[13] = { Wd4, WtD4, 32, 16 };
    wprep_all_k<<<dim3(128, 14), 256, 0, stream>>>(wa);

    int ntile = (N + 127)/128;
    fused_input_k<<<ntile, 256, 0, stream>>>(x, WtIN, b_in, Wt8, hG, N);

    for (int i = 0; i < KHOP; ++i){
        gcn_agg_h<<<(N+15)/16, 256, 0, stream>>>(hG, hG2, rowptr, csr_src, dinv, b_gcn, N);
        const float* eps_i = eps + (size_t)i*NN;
        if (i == KHOP-1)
            hop2_k<1><<<ntile, 256, 0, stream>>>(hG2, Wt8, b_enc, b_mu, b_std, eps_i,
                                                 nullptr, out_mu, out_std, hH, N);
        else
            hop2_k<0><<<ntile, 256, 0, stream>>>(hG2, Wt8, b_enc, b_mu, b_std, eps_i,
                                                 hG, nullptr, nullptr, nullptr, N);
    }

    decoder_k<<<(N+63)/64, 256, 0, stream>>>(hH, WtD0, WtD1, WtD2, WtD3, WtD4,
                                             bd0, bd1, bd2, bd3, bd4, Wo, bo,
                                             batch, out_ypred, gcnt, N);
    divide_k<<<(G*DOUT+255)/256, 256, 0, stream>>>(out_ypred, gcnt, G*DOUT);
    copy_k<<<(G*DOUT+255)/256, 256, 0, stream>>>(y, out_y, G*DOUT);
}